// Round 1
// baseline (3014.741 us; speedup 1.0000x reference)
//
#include <hip/hip_runtime.h>

#define NN 100000
#define NE 1600000
#define H  128

// ---------------- zero agg ----------------
__global__ void zero_kernel(float4* __restrict__ p, long long n4) {
    long long i = (long long)blockIdx.x * blockDim.x + threadIdx.x;
    if (i < n4) p[i] = float4{0.f, 0.f, 0.f, 0.f};
}

// ---------------- precompute W3 = W_node @ (I + W_cat2) ----------------
__global__ void precompute_w3(const float* __restrict__ W_node,
                              const float* __restrict__ W_cat2,
                              float* __restrict__ W3) {
    int k = blockIdx.x;   // row 0..127
    int c = threadIdx.x;  // col 0..127
    __shared__ float wrow[H];
    wrow[c] = W_node[k * H + c];
    __syncthreads();
    float acc = wrow[c];  // identity part
    #pragma unroll 8
    for (int j = 0; j < H; ++j)
        acc += wrow[j] * W_cat2[j * H + c];
    W3[k * H + c] = acc;
}

// b4 = b_edge + b_edge@W_cat1 + b_cat1 + b_node + b_node@W_cat2 + b_cat2
__global__ void precompute_b4(const float* __restrict__ b_edge,
                              const float* __restrict__ W_cat1,
                              const float* __restrict__ b_node,
                              const float* __restrict__ W_cat2,
                              const float* __restrict__ b_cat1,
                              const float* __restrict__ b_cat2,
                              float* __restrict__ b4) {
    int c = threadIdx.x;
    __shared__ float be[H], bn[H];
    be[c] = b_edge[c];
    bn[c] = b_node[c];
    __syncthreads();
    float acc = be[c] + bn[c] + b_cat1[c] + b_cat2[c];
    for (int j = 0; j < H; ++j)
        acc += be[j] * W_cat1[j * H + c] + bn[j] * W_cat2[j * H + c];
    b4[c] = acc;
}

// ---------------- scatter: agg[dst] += w * W_edge[src] ----------------
// 8 edges per 256-thread block; 32 lanes x float4 cover the 128 channels.
__global__ void scatter_edges(const int* __restrict__ ei,
                              const float* __restrict__ ew,
                              const float* __restrict__ W_edge,
                              float* __restrict__ agg) {
    int slot = threadIdx.x >> 5;
    long long e = (long long)blockIdx.x * 8 + slot;
    if (e >= NE) return;
    int c4 = (threadIdx.x & 31) * 4;
    int s = ei[e];
    int d = ei[NE + e];
    float w = ew[e];
    float4 v = *reinterpret_cast<const float4*>(&W_edge[(long long)s * H + c4]);
    float* dst = &agg[(long long)d * H + c4];
    atomicAdd(dst + 0, w * v.x);
    atomicAdd(dst + 1, w * v.y);
    atomicAdd(dst + 2, w * v.z);
    atomicAdd(dst + 3, w * v.w);
}

// ---------------- P1: r = relu(agg + agg@Wc1 + x@W3 + b4) ----------------
// 16 rows per block. Thread t: cols {2*(t&63), 2*(t&63)+1}, rows (t>>6)*4 .. +3.
__global__ __launch_bounds__(256) void fused_p1(const float* __restrict__ agg,
                                                const float* __restrict__ x,
                                                const float* __restrict__ Wc1,
                                                const float* __restrict__ W3,
                                                const float* __restrict__ b4,
                                                float* __restrict__ r_out,
                                                int nrows) {
    const int TR = 16;
    __shared__ float As[TR][H];
    __shared__ float Xs[TR][H];
    int row0 = blockIdx.x * TR;
    int tid = threadIdx.x;

    for (int i = tid; i < TR * H / 4; i += 256) {
        int fi = i * 4;
        int rr = fi >> 7, cc = fi & 127;
        if (row0 + rr < nrows) {
            long long g = (long long)(row0 + rr) * H + cc;
            *reinterpret_cast<float4*>(&As[rr][cc]) = *reinterpret_cast<const float4*>(&agg[g]);
            *reinterpret_cast<float4*>(&Xs[rr][cc]) = *reinterpret_cast<const float4*>(&x[g]);
        } else {
            *reinterpret_cast<float4*>(&As[rr][cc]) = float4{0.f, 0.f, 0.f, 0.f};
            *reinterpret_cast<float4*>(&Xs[rr][cc]) = float4{0.f, 0.f, 0.f, 0.f};
        }
    }
    __syncthreads();

    int c2 = (tid & 63) * 2;
    int rbase = (tid >> 6) * 4;
    float2 b4v = *reinterpret_cast<const float2*>(&b4[c2]);
    float acc[4][2];
    #pragma unroll
    for (int r = 0; r < 4; ++r) {
        acc[r][0] = As[rbase + r][c2]     + b4v.x;  // identity term of (I + W_cat1)
        acc[r][1] = As[rbase + r][c2 + 1] + b4v.y;
    }

    for (int k = 0; k < H; k += 4) {
        float2 w1[4], w3[4];
        #pragma unroll
        for (int kk = 0; kk < 4; ++kk) {
            w1[kk] = *reinterpret_cast<const float2*>(&Wc1[(k + kk) * H + c2]);
            w3[kk] = *reinterpret_cast<const float2*>(&W3[(k + kk) * H + c2]);
        }
        #pragma unroll
        for (int r = 0; r < 4; ++r) {
            float4 a  = *reinterpret_cast<const float4*>(&As[rbase + r][k]);
            float4 xv = *reinterpret_cast<const float4*>(&Xs[rbase + r][k]);
            acc[r][0] += a.x * w1[0].x + a.y * w1[1].x + a.z * w1[2].x + a.w * w1[3].x
                       + xv.x * w3[0].x + xv.y * w3[1].x + xv.z * w3[2].x + xv.w * w3[3].x;
            acc[r][1] += a.x * w1[0].y + a.y * w1[1].y + a.z * w1[2].y + a.w * w1[3].y
                       + xv.x * w3[0].y + xv.y * w3[1].y + xv.z * w3[2].y + xv.w * w3[3].y;
        }
    }

    #pragma unroll
    for (int r = 0; r < 4; ++r) {
        int row = row0 + rbase + r;
        if (row < nrows) {
            float2 o;
            o.x = fmaxf(acc[r][0], 0.f);
            o.y = fmaxf(acc[r][1], 0.f);
            *reinterpret_cast<float2*>(&r_out[(long long)row * H + c2]) = o;
        }
    }
}

// ---------------- P2 (in-place): io = io @ W_final + b_final ----------------
__global__ __launch_bounds__(256) void fused_p2(float* __restrict__ io,
                                                const float* __restrict__ Wf,
                                                const float* __restrict__ bf,
                                                int nrows) {
    const int TR = 16;
    __shared__ float Rs[TR][H];
    int row0 = blockIdx.x * TR;
    int tid = threadIdx.x;

    for (int i = tid; i < TR * H / 4; i += 256) {
        int fi = i * 4;
        int rr = fi >> 7, cc = fi & 127;
        if (row0 + rr < nrows) {
            long long g = (long long)(row0 + rr) * H + cc;
            *reinterpret_cast<float4*>(&Rs[rr][cc]) = *reinterpret_cast<const float4*>(&io[g]);
        } else {
            *reinterpret_cast<float4*>(&Rs[rr][cc]) = float4{0.f, 0.f, 0.f, 0.f};
        }
    }
    __syncthreads();

    int c2 = (tid & 63) * 2;
    int rbase = (tid >> 6) * 4;
    float2 bfv = *reinterpret_cast<const float2*>(&bf[c2]);
    float acc[4][2];
    #pragma unroll
    for (int r = 0; r < 4; ++r) {
        acc[r][0] = bfv.x;
        acc[r][1] = bfv.y;
    }

    for (int k = 0; k < H; k += 4) {
        float2 wf[4];
        #pragma unroll
        for (int kk = 0; kk < 4; ++kk)
            wf[kk] = *reinterpret_cast<const float2*>(&Wf[(k + kk) * H + c2]);
        #pragma unroll
        for (int r = 0; r < 4; ++r) {
            float4 v = *reinterpret_cast<const float4*>(&Rs[rbase + r][k]);
            acc[r][0] += v.x * wf[0].x + v.y * wf[1].x + v.z * wf[2].x + v.w * wf[3].x;
            acc[r][1] += v.x * wf[0].y + v.y * wf[1].y + v.z * wf[2].y + v.w * wf[3].y;
        }
    }

    #pragma unroll
    for (int r = 0; r < 4; ++r) {
        int row = row0 + rbase + r;
        if (row < nrows) {
            float2 o{acc[r][0], acc[r][1]};
            *reinterpret_cast<float2*>(&io[(long long)row * H + c2]) = o;
        }
    }
}

extern "C" void kernel_launch(void* const* d_in, const int* in_sizes, int n_in,
                              void* d_out, int out_size, void* d_ws, size_t ws_size,
                              hipStream_t stream) {
    const float* x       = (const float*)d_in[0];
    const int*   ei      = (const int*)d_in[1];   // int32 (JAX x64 disabled)
    const float* ew      = (const float*)d_in[2];
    const float* W_edge  = (const float*)d_in[3];
    const float* b_edge  = (const float*)d_in[4];
    const float* W_node  = (const float*)d_in[5];
    const float* b_node  = (const float*)d_in[6];
    const float* W_cat1  = (const float*)d_in[7];
    const float* b_cat1  = (const float*)d_in[8];
    const float* W_cat2  = (const float*)d_in[9];
    const float* b_cat2  = (const float*)d_in[10];
    const float* W_final = (const float*)d_in[11];
    const float* b_final = (const float*)d_in[12];
    float* out = (float*)d_out;

    float* agg = (float*)d_ws;                       // N*H floats
    float* W3  = agg + (size_t)NN * H;               // H*H floats
    float* b4  = W3 + (size_t)H * H;                 // H floats

    // zero accumulator
    long long n4 = (long long)NN * H / 4;
    zero_kernel<<<(int)((n4 + 255) / 256), 256, 0, stream>>>((float4*)agg, n4);

    // tiny precomputes
    precompute_w3<<<H, H, 0, stream>>>(W_node, W_cat2, W3);
    precompute_b4<<<1, H, 0, stream>>>(b_edge, W_cat1, b_node, W_cat2, b_cat1, b_cat2, b4);

    // scatter-add SpMM
    scatter_edges<<<NE / 8, 256, 0, stream>>>(ei, ew, W_edge, agg);

    // fused affine pass + relu -> d_out
    fused_p1<<<(NN + 15) / 16, 256, 0, stream>>>(agg, x, W_cat1, W3, b4, out, NN);

    // final linear, in-place on d_out
    fused_p2<<<(NN + 15) / 16, 256, 0, stream>>>(out, W_final, b_final, NN);
}

// Round 2
// 575.961 us; speedup vs baseline: 5.2343x; 5.2343x over previous
//
#include <hip/hip_runtime.h>

#define NN 100000
#define NE 1600000
#define H  128
#define SCAN_CHUNK 512
#define NB_SCAN ((NN + SCAN_CHUNK - 1) / SCAN_CHUNK)   // 196

// ---------------- zero int array ----------------
__global__ void zero_int(int* __restrict__ p, int n) {
    int i = blockIdx.x * blockDim.x + threadIdx.x;
    if (i < n) p[i] = 0;
}

// ---------------- histogram of dst ----------------
__global__ void hist_kernel(const int* __restrict__ ei, int* __restrict__ deg) {
    int e = blockIdx.x * 256 + threadIdx.x;
    if (e < NE) atomicAdd(&deg[ei[NE + e]], 1);
}

// ---------------- per-chunk exclusive scan (Hillis-Steele) ----------------
__global__ __launch_bounds__(SCAN_CHUNK) void scan_block(const int* __restrict__ deg,
                                                         int* __restrict__ off,
                                                         int* __restrict__ sums, int n) {
    __shared__ int buf[SCAN_CHUNK];
    int base = blockIdx.x * SCAN_CHUNK;
    int t = threadIdx.x;
    int v = (base + t < n) ? deg[base + t] : 0;
    buf[t] = v;
    __syncthreads();
    for (int s = 1; s < SCAN_CHUNK; s <<= 1) {
        int add = (t >= s) ? buf[t - s] : 0;
        __syncthreads();
        buf[t] += add;
        __syncthreads();
    }
    if (base + t < n) off[base + t] = buf[t] - v;   // exclusive within chunk
    if (t == SCAN_CHUNK - 1) sums[blockIdx.x] = buf[t];
}

// ---------------- scan the chunk sums (single block, in place) ----------------
__global__ __launch_bounds__(256) void scan_sums(int* __restrict__ sums, int nb) {
    __shared__ int buf[256];
    int t = threadIdx.x;
    int v = (t < nb) ? sums[t] : 0;
    buf[t] = v;
    __syncthreads();
    for (int s = 1; s < 256; s <<= 1) {
        int add = (t >= s) ? buf[t - s] : 0;
        __syncthreads();
        buf[t] += add;
        __syncthreads();
    }
    if (t < nb) sums[t] = buf[t] - v;               // exclusive
}

// ---------------- add chunk offsets; init cursor ----------------
__global__ void scan_add(int* __restrict__ off, const int* __restrict__ sums,
                         int* __restrict__ cur, int n) {
    int i = blockIdx.x * 256 + threadIdx.x;
    if (i < n) {
        int v = off[i] + sums[i >> 9];              // SCAN_CHUNK = 512
        off[i] = v;
        cur[i] = v;
    }
}

// ---------------- fill CSR with packed (src, weight) ----------------
__global__ void fill_kernel(const int* __restrict__ ei, const float* __restrict__ ew,
                            int* __restrict__ cur, int2* __restrict__ csr) {
    int e = blockIdx.x * 256 + threadIdx.x;
    if (e >= NE) return;
    int d = ei[NE + e];
    int pos = atomicAdd(&cur[d], 1);
    csr[pos] = make_int2(ei[e], __float_as_int(ew[e]));
}

// ---------------- precompute W3 = W_node @ (I + W_cat2) ----------------
__global__ void precompute_w3(const float* __restrict__ W_node,
                              const float* __restrict__ W_cat2,
                              float* __restrict__ W3) {
    int k = blockIdx.x;
    int c = threadIdx.x;
    __shared__ float wrow[H];
    wrow[c] = W_node[k * H + c];
    __syncthreads();
    float acc = wrow[c];
    #pragma unroll 8
    for (int j = 0; j < H; ++j)
        acc += wrow[j] * W_cat2[j * H + c];
    W3[k * H + c] = acc;
}

__global__ void precompute_b4(const float* __restrict__ b_edge,
                              const float* __restrict__ W_cat1,
                              const float* __restrict__ b_node,
                              const float* __restrict__ W_cat2,
                              const float* __restrict__ b_cat1,
                              const float* __restrict__ b_cat2,
                              float* __restrict__ b4) {
    int c = threadIdx.x;
    __shared__ float be[H], bn[H];
    be[c] = b_edge[c];
    bn[c] = b_node[c];
    __syncthreads();
    float acc = be[c] + bn[c] + b_cat1[c] + b_cat2[c];
    for (int j = 0; j < H; ++j)
        acc += be[j] * W_cat1[j * H + c] + bn[j] * W_cat2[j * H + c];
    b4[c] = acc;
}

// ------- fused gather + P1: r = relu(agg + agg@Wc1 + x@W3 + b4) -------
// 16 nodes/block. Phase A: 8 groups of 32 lanes gather 2 nodes each into As.
// Phase B: per-row GEMV over Wc1 (agg branch) and W3 (x branch), relu, store.
__global__ __launch_bounds__(256) void gather_p1(const int* __restrict__ off,
                                                 const int* __restrict__ end,
                                                 const int2* __restrict__ csr,
                                                 const float* __restrict__ W_edge,
                                                 const float* __restrict__ x,
                                                 const float* __restrict__ Wc1,
                                                 const float* __restrict__ W3,
                                                 const float* __restrict__ b4,
                                                 float* __restrict__ r_out,
                                                 int nrows) {
    const int TR = 16;
    __shared__ float As[TR][H];
    __shared__ float Xs[TR][H];
    int row0 = blockIdx.x * TR;
    int tid = threadIdx.x;

    // load Xs (x rows)
    for (int i = tid; i < TR * H / 4; i += 256) {
        int fi = i * 4;
        int rr = fi >> 7, cc = fi & 127;
        float4 xv = {0.f, 0.f, 0.f, 0.f};
        if (row0 + rr < nrows)
            xv = *reinterpret_cast<const float4*>(&x[(long long)(row0 + rr) * H + cc]);
        *reinterpret_cast<float4*>(&Xs[rr][cc]) = xv;
    }

    // gather As (edge aggregation)
    int g = tid >> 5, lane = tid & 31;
    int c4 = lane * 4;
    #pragma unroll
    for (int sub = 0; sub < 2; ++sub) {
        int lr = g * 2 + sub;
        int d = row0 + lr;
        float4 acc = {0.f, 0.f, 0.f, 0.f};
        if (d < nrows) {
            int i0 = off[d], i1 = end[d];
            for (int base = i0; base < i1; base += 32) {
                int m = i1 - base;
                if (m > 32) m = 32;
                int2 ent = (lane < m) ? csr[base + lane] : make_int2(0, 0);
                for (int j = 0; j < m; ++j) {
                    int src = __shfl(ent.x, j, 32);
                    float w = __int_as_float(__shfl(ent.y, j, 32));
                    float4 v = *reinterpret_cast<const float4*>(&W_edge[(long long)src * H + c4]);
                    acc.x += w * v.x;
                    acc.y += w * v.y;
                    acc.z += w * v.z;
                    acc.w += w * v.w;
                }
            }
        }
        *reinterpret_cast<float4*>(&As[lr][c4]) = acc;
    }
    __syncthreads();

    // Phase B: GEMV
    int c2 = (tid & 63) * 2;
    int rbase = (tid >> 6) * 4;
    float2 b4v = *reinterpret_cast<const float2*>(&b4[c2]);
    float acc[4][2];
    #pragma unroll
    for (int r = 0; r < 4; ++r) {
        acc[r][0] = As[rbase + r][c2]     + b4v.x;   // identity term of (I + W_cat1)
        acc[r][1] = As[rbase + r][c2 + 1] + b4v.y;
    }

    for (int k = 0; k < H; k += 4) {
        float2 w1[4], w3[4];
        #pragma unroll
        for (int kk = 0; kk < 4; ++kk) {
            w1[kk] = *reinterpret_cast<const float2*>(&Wc1[(k + kk) * H + c2]);
            w3[kk] = *reinterpret_cast<const float2*>(&W3[(k + kk) * H + c2]);
        }
        #pragma unroll
        for (int r = 0; r < 4; ++r) {
            float4 a  = *reinterpret_cast<const float4*>(&As[rbase + r][k]);
            float4 xv = *reinterpret_cast<const float4*>(&Xs[rbase + r][k]);
            acc[r][0] += a.x * w1[0].x + a.y * w1[1].x + a.z * w1[2].x + a.w * w1[3].x
                       + xv.x * w3[0].x + xv.y * w3[1].x + xv.z * w3[2].x + xv.w * w3[3].x;
            acc[r][1] += a.x * w1[0].y + a.y * w1[1].y + a.z * w1[2].y + a.w * w1[3].y
                       + xv.x * w3[0].y + xv.y * w3[1].y + xv.z * w3[2].y + xv.w * w3[3].y;
        }
    }

    #pragma unroll
    for (int r = 0; r < 4; ++r) {
        int row = row0 + rbase + r;
        if (row < nrows) {
            float2 o;
            o.x = fmaxf(acc[r][0], 0.f);
            o.y = fmaxf(acc[r][1], 0.f);
            *reinterpret_cast<float2*>(&r_out[(long long)row * H + c2]) = o;
        }
    }
}

// ---------------- P2 (in-place): io = io @ W_final + b_final ----------------
__global__ __launch_bounds__(256) void fused_p2(float* __restrict__ io,
                                                const float* __restrict__ Wf,
                                                const float* __restrict__ bf,
                                                int nrows) {
    const int TR = 16;
    __shared__ float Rs[TR][H];
    int row0 = blockIdx.x * TR;
    int tid = threadIdx.x;

    for (int i = tid; i < TR * H / 4; i += 256) {
        int fi = i * 4;
        int rr = fi >> 7, cc = fi & 127;
        float4 v = {0.f, 0.f, 0.f, 0.f};
        if (row0 + rr < nrows)
            v = *reinterpret_cast<const float4*>(&io[(long long)(row0 + rr) * H + cc]);
        *reinterpret_cast<float4*>(&Rs[rr][cc]) = v;
    }
    __syncthreads();

    int c2 = (tid & 63) * 2;
    int rbase = (tid >> 6) * 4;
    float2 bfv = *reinterpret_cast<const float2*>(&bf[c2]);
    float acc[4][2];
    #pragma unroll
    for (int r = 0; r < 4; ++r) {
        acc[r][0] = bfv.x;
        acc[r][1] = bfv.y;
    }

    for (int k = 0; k < H; k += 4) {
        float2 wf[4];
        #pragma unroll
        for (int kk = 0; kk < 4; ++kk)
            wf[kk] = *reinterpret_cast<const float2*>(&Wf[(k + kk) * H + c2]);
        #pragma unroll
        for (int r = 0; r < 4; ++r) {
            float4 v = *reinterpret_cast<const float4*>(&Rs[rbase + r][k]);
            acc[r][0] += v.x * wf[0].x + v.y * wf[1].x + v.z * wf[2].x + v.w * wf[3].x;
            acc[r][1] += v.x * wf[0].y + v.y * wf[1].y + v.z * wf[2].y + v.w * wf[3].y;
        }
    }

    __syncthreads();
    #pragma unroll
    for (int r = 0; r < 4; ++r) {
        int row = row0 + rbase + r;
        if (row < nrows) {
            float2 o{acc[r][0], acc[r][1]};
            *reinterpret_cast<float2*>(&io[(long long)row * H + c2]) = o;
        }
    }
}

extern "C" void kernel_launch(void* const* d_in, const int* in_sizes, int n_in,
                              void* d_out, int out_size, void* d_ws, size_t ws_size,
                              hipStream_t stream) {
    const float* x       = (const float*)d_in[0];
    const int*   ei      = (const int*)d_in[1];   // int32 (JAX x64 disabled)
    const float* ew      = (const float*)d_in[2];
    const float* W_edge  = (const float*)d_in[3];
    const float* b_edge  = (const float*)d_in[4];
    const float* W_node  = (const float*)d_in[5];
    const float* b_node  = (const float*)d_in[6];
    const float* W_cat1  = (const float*)d_in[7];
    const float* b_cat1  = (const float*)d_in[8];
    const float* W_cat2  = (const float*)d_in[9];
    const float* b_cat2  = (const float*)d_in[10];
    const float* W_final = (const float*)d_in[11];
    const float* b_final = (const float*)d_in[12];
    float* out = (float*)d_out;

    // workspace layout (ints are 4B; csr needs 8B alignment -- offset 1202048 % 8 == 0)
    int*  deg  = (int*)d_ws;                 // NN
    int*  off  = deg + NN;                   // NN
    int*  cur  = off + NN;                   // NN
    int*  sums = cur + NN;                   // 512
    int2* csr  = (int2*)(sums + 512);        // NE
    float* W3  = (float*)(csr + NE);         // H*H
    float* b4  = W3 + H * H;                 // H

    // 1. CSR build
    zero_int<<<(NN + 255) / 256, 256, 0, stream>>>(deg, NN);
    hist_kernel<<<(NE + 255) / 256, 256, 0, stream>>>(ei, deg);
    scan_block<<<NB_SCAN, SCAN_CHUNK, 0, stream>>>(deg, off, sums, NN);
    scan_sums<<<1, 256, 0, stream>>>(sums, NB_SCAN);
    scan_add<<<(NN + 255) / 256, 256, 0, stream>>>(off, sums, cur, NN);
    fill_kernel<<<(NE + 255) / 256, 256, 0, stream>>>(ei, ew, cur, csr);

    // 2. tiny precomputes
    precompute_w3<<<H, H, 0, stream>>>(W_node, W_cat2, W3);
    precompute_b4<<<1, H, 0, stream>>>(b_edge, W_cat1, b_node, W_cat2, b_cat1, b_cat2, b4);

    // 3. fused gather + affine + relu -> d_out   (cur now holds segment ends)
    gather_p1<<<(NN + 15) / 16, 256, 0, stream>>>(off, cur, csr, W_edge, x,
                                                  W_cat1, W3, b4, out, NN);

    // 4. final linear, in-place on d_out
    fused_p2<<<(NN + 15) / 16, 256, 0, stream>>>(out, W_final, b_final, NN);
}

// Round 3
// 537.491 us; speedup vs baseline: 5.6089x; 1.0716x over previous
//
#include <hip/hip_runtime.h>

#define NN 100000
#define NE 1600000
#define H  128
#define SCAN_CHUNK 512
#define NB_SCAN ((NN + SCAN_CHUNK - 1) / SCAN_CHUNK)   // 196

// ---------------- zero int array ----------------
__global__ void zero_int(int* __restrict__ p, int n) {
    int i = blockIdx.x * blockDim.x + threadIdx.x;
    if (i < n) p[i] = 0;
}

// ---------------- histogram of dst ----------------
__global__ void hist_kernel(const int* __restrict__ ei, int* __restrict__ deg) {
    int e = blockIdx.x * 256 + threadIdx.x;
    if (e < NE) atomicAdd(&deg[ei[NE + e]], 1);
}

// ---------------- per-chunk exclusive scan ----------------
__global__ __launch_bounds__(SCAN_CHUNK) void scan_block(const int* __restrict__ deg,
                                                         int* __restrict__ off,
                                                         int* __restrict__ sums, int n) {
    __shared__ int buf[SCAN_CHUNK];
    int base = blockIdx.x * SCAN_CHUNK;
    int t = threadIdx.x;
    int v = (base + t < n) ? deg[base + t] : 0;
    buf[t] = v;
    __syncthreads();
    for (int s = 1; s < SCAN_CHUNK; s <<= 1) {
        int add = (t >= s) ? buf[t - s] : 0;
        __syncthreads();
        buf[t] += add;
        __syncthreads();
    }
    if (base + t < n) off[base + t] = buf[t] - v;
    if (t == SCAN_CHUNK - 1) sums[blockIdx.x] = buf[t];
}

__global__ __launch_bounds__(256) void scan_sums(int* __restrict__ sums, int nb) {
    __shared__ int buf[256];
    int t = threadIdx.x;
    int v = (t < nb) ? sums[t] : 0;
    buf[t] = v;
    __syncthreads();
    for (int s = 1; s < 256; s <<= 1) {
        int add = (t >= s) ? buf[t - s] : 0;
        __syncthreads();
        buf[t] += add;
        __syncthreads();
    }
    if (t < nb) sums[t] = buf[t] - v;
}

__global__ void scan_add(int* __restrict__ off, const int* __restrict__ sums,
                         int* __restrict__ cur, int n) {
    int i = blockIdx.x * 256 + threadIdx.x;
    if (i < n) {
        int v = off[i] + sums[i >> 9];
        off[i] = v;
        cur[i] = v;
    }
}

// ---------------- fill CSR with packed (src, weight) ----------------
__global__ void fill_kernel(const int* __restrict__ ei, const float* __restrict__ ew,
                            int* __restrict__ cur, int2* __restrict__ csr) {
    int e = blockIdx.x * 256 + threadIdx.x;
    if (e >= NE) return;
    int d = ei[NE + e];
    int pos = atomicAdd(&cur[d], 1);
    csr[pos] = make_int2(ei[e], __float_as_int(ew[e]));
}

// ---------------- precompute W3 = W_node @ (I + W_cat2) ----------------
__global__ void precompute_w3(const float* __restrict__ W_node,
                              const float* __restrict__ W_cat2,
                              float* __restrict__ W3) {
    int k = blockIdx.x;
    int c = threadIdx.x;
    __shared__ float wrow[H];
    wrow[c] = W_node[k * H + c];
    __syncthreads();
    float acc = wrow[c];
    #pragma unroll 8
    for (int j = 0; j < H; ++j)
        acc += wrow[j] * W_cat2[j * H + c];
    W3[k * H + c] = acc;
}

__global__ void precompute_b4(const float* __restrict__ b_edge,
                              const float* __restrict__ W_cat1,
                              const float* __restrict__ b_node,
                              const float* __restrict__ W_cat2,
                              const float* __restrict__ b_cat1,
                              const float* __restrict__ b_cat2,
                              float* __restrict__ b4) {
    int c = threadIdx.x;
    __shared__ float be[H], bn[H];
    be[c] = b_edge[c];
    bn[c] = b_node[c];
    __syncthreads();
    float acc = be[c] + bn[c] + b_cat1[c] + b_cat2[c];
    for (int j = 0; j < H; ++j)
        acc += be[j] * W_cat1[j * H + c] + bn[j] * W_cat2[j * H + c];
    b4[c] = acc;
}

// ------- fully fused: gather + (t4 = agg + agg@Wc1 + x@W3 + b4) + relu + @Wf + bf -------
__global__ __launch_bounds__(256) void gather_fused(const int* __restrict__ off,
                                                    const int* __restrict__ end,
                                                    const int2* __restrict__ csr,
                                                    const float* __restrict__ W_edge,
                                                    const float* __restrict__ x,
                                                    const float* __restrict__ Wc1,
                                                    const float* __restrict__ W3,
                                                    const float* __restrict__ b4,
                                                    const float* __restrict__ Wf,
                                                    const float* __restrict__ bf,
                                                    float* __restrict__ out,
                                                    int nrows) {
    const int TR = 16;
    __shared__ float As[TR][H];
    __shared__ float Xs[TR][H];
    int row0 = blockIdx.x * TR;
    int tid = threadIdx.x;

    // load Xs (x rows)
    for (int i = tid; i < TR * H / 4; i += 256) {
        int fi = i * 4;
        int rr = fi >> 7, cc = fi & 127;
        float4 xv = {0.f, 0.f, 0.f, 0.f};
        if (row0 + rr < nrows)
            xv = *reinterpret_cast<const float4*>(&x[(long long)(row0 + rr) * H + cc]);
        *reinterpret_cast<float4*>(&Xs[rr][cc]) = xv;
    }

    // ---- phase A: gather, 8-deep batched loads for MLP ----
    int g = tid >> 5, lane = tid & 31;
    int c4 = lane * 4;
    #pragma unroll
    for (int sub = 0; sub < 2; ++sub) {
        int lr = g * 2 + sub;
        int d = row0 + lr;
        float4 acc = {0.f, 0.f, 0.f, 0.f};
        if (d < nrows) {
            int i0 = off[d], i1 = end[d];
            for (int base = i0; base < i1; base += 32) {
                int mm = i1 - base;
                if (mm > 32) mm = 32;
                int2 ent = (lane < mm) ? csr[base + lane] : make_int2(0, 0);
                int j = 0;
                for (; j + 8 <= mm; j += 8) {
                    float4 v[8];
                    float w[8];
                    #pragma unroll
                    for (int u = 0; u < 8; ++u) {
                        int src = __shfl(ent.x, j + u, 32);
                        w[u] = __int_as_float(__shfl(ent.y, j + u, 32));
                        v[u] = *reinterpret_cast<const float4*>(&W_edge[(long long)src * H + c4]);
                    }
                    #pragma unroll
                    for (int u = 0; u < 8; ++u) {
                        acc.x += w[u] * v[u].x;
                        acc.y += w[u] * v[u].y;
                        acc.z += w[u] * v[u].z;
                        acc.w += w[u] * v[u].w;
                    }
                }
                for (; j + 2 <= mm; j += 2) {
                    float4 v[2];
                    float w[2];
                    #pragma unroll
                    for (int u = 0; u < 2; ++u) {
                        int src = __shfl(ent.x, j + u, 32);
                        w[u] = __int_as_float(__shfl(ent.y, j + u, 32));
                        v[u] = *reinterpret_cast<const float4*>(&W_edge[(long long)src * H + c4]);
                    }
                    #pragma unroll
                    for (int u = 0; u < 2; ++u) {
                        acc.x += w[u] * v[u].x;
                        acc.y += w[u] * v[u].y;
                        acc.z += w[u] * v[u].z;
                        acc.w += w[u] * v[u].w;
                    }
                }
                if (j < mm) {
                    int src = __shfl(ent.x, j, 32);
                    float w1 = __int_as_float(__shfl(ent.y, j, 32));
                    float4 v = *reinterpret_cast<const float4*>(&W_edge[(long long)src * H + c4]);
                    acc.x += w1 * v.x;
                    acc.y += w1 * v.y;
                    acc.z += w1 * v.z;
                    acc.w += w1 * v.w;
                }
            }
        }
        *reinterpret_cast<float4*>(&As[lr][c4]) = acc;
    }
    __syncthreads();

    // ---- phase B: t4 = agg + agg@Wc1 + x@W3 + b4 ----
    int c2 = (tid & 63) * 2;
    int rbase = (tid >> 6) * 4;
    float2 b4v = *reinterpret_cast<const float2*>(&b4[c2]);
    float acc[4][2];
    #pragma unroll
    for (int r = 0; r < 4; ++r) {
        acc[r][0] = As[rbase + r][c2]     + b4v.x;   // identity term of (I + W_cat1)
        acc[r][1] = As[rbase + r][c2 + 1] + b4v.y;
    }

    for (int k = 0; k < H; k += 4) {
        float2 w1[4], w3[4];
        #pragma unroll
        for (int kk = 0; kk < 4; ++kk) {
            w1[kk] = *reinterpret_cast<const float2*>(&Wc1[(k + kk) * H + c2]);
            w3[kk] = *reinterpret_cast<const float2*>(&W3[(k + kk) * H + c2]);
        }
        #pragma unroll
        for (int r = 0; r < 4; ++r) {
            float4 a  = *reinterpret_cast<const float4*>(&As[rbase + r][k]);
            float4 xv = *reinterpret_cast<const float4*>(&Xs[rbase + r][k]);
            acc[r][0] += a.x * w1[0].x + a.y * w1[1].x + a.z * w1[2].x + a.w * w1[3].x
                       + xv.x * w3[0].x + xv.y * w3[1].x + xv.z * w3[2].x + xv.w * w3[3].x;
            acc[r][1] += a.x * w1[0].y + a.y * w1[1].y + a.z * w1[2].y + a.w * w1[3].y
                       + xv.x * w3[0].y + xv.y * w3[1].y + xv.z * w3[2].y + xv.w * w3[3].y;
        }
    }

    // ---- relu, stash back to LDS ----
    __syncthreads();   // all phase-B reads of As complete
    #pragma unroll
    for (int r = 0; r < 4; ++r) {
        As[rbase + r][c2]     = fmaxf(acc[r][0], 0.f);
        As[rbase + r][c2 + 1] = fmaxf(acc[r][1], 0.f);
    }
    __syncthreads();

    // ---- phase C: out = relu(t4) @ Wf + bf ----
    float2 bfv = *reinterpret_cast<const float2*>(&bf[c2]);
    float acc2[4][2];
    #pragma unroll
    for (int r = 0; r < 4; ++r) {
        acc2[r][0] = bfv.x;
        acc2[r][1] = bfv.y;
    }

    for (int k = 0; k < H; k += 4) {
        float2 wf[4];
        #pragma unroll
        for (int kk = 0; kk < 4; ++kk)
            wf[kk] = *reinterpret_cast<const float2*>(&Wf[(k + kk) * H + c2]);
        #pragma unroll
        for (int r = 0; r < 4; ++r) {
            float4 v = *reinterpret_cast<const float4*>(&As[rbase + r][k]);
            acc2[r][0] += v.x * wf[0].x + v.y * wf[1].x + v.z * wf[2].x + v.w * wf[3].x;
            acc2[r][1] += v.x * wf[0].y + v.y * wf[1].y + v.z * wf[2].y + v.w * wf[3].y;
        }
    }

    #pragma unroll
    for (int r = 0; r < 4; ++r) {
        int row = row0 + rbase + r;
        if (row < nrows) {
            float2 o{acc2[r][0], acc2[r][1]};
            *reinterpret_cast<float2*>(&out[(long long)row * H + c2]) = o;
        }
    }
}

extern "C" void kernel_launch(void* const* d_in, const int* in_sizes, int n_in,
                              void* d_out, int out_size, void* d_ws, size_t ws_size,
                              hipStream_t stream) {
    const float* x       = (const float*)d_in[0];
    const int*   ei      = (const int*)d_in[1];
    const float* ew      = (const float*)d_in[2];
    const float* W_edge  = (const float*)d_in[3];
    const float* b_edge  = (const float*)d_in[4];
    const float* W_node  = (const float*)d_in[5];
    const float* b_node  = (const float*)d_in[6];
    const float* W_cat1  = (const float*)d_in[7];
    const float* b_cat1  = (const float*)d_in[8];
    const float* W_cat2  = (const float*)d_in[9];
    const float* b_cat2  = (const float*)d_in[10];
    const float* W_final = (const float*)d_in[11];
    const float* b_final = (const float*)d_in[12];
    float* out = (float*)d_out;

    int*  deg  = (int*)d_ws;                 // NN
    int*  off  = deg + NN;                   // NN
    int*  cur  = off + NN;                   // NN
    int*  sums = cur + NN;                   // 512
    int2* csr  = (int2*)(sums + 512);        // NE
    float* W3  = (float*)(csr + NE);         // H*H
    float* b4  = W3 + H * H;                 // H

    // 1. CSR build
    zero_int<<<(NN + 255) / 256, 256, 0, stream>>>(deg, NN);
    hist_kernel<<<(NE + 255) / 256, 256, 0, stream>>>(ei, deg);
    scan_block<<<NB_SCAN, SCAN_CHUNK, 0, stream>>>(deg, off, sums, NN);
    scan_sums<<<1, 256, 0, stream>>>(sums, NB_SCAN);
    scan_add<<<(NN + 255) / 256, 256, 0, stream>>>(off, sums, cur, NN);
    fill_kernel<<<(NE + 255) / 256, 256, 0, stream>>>(ei, ew, cur, csr);

    // 2. tiny precomputes
    precompute_w3<<<H, H, 0, stream>>>(W_node, W_cat2, W3);
    precompute_b4<<<1, H, 0, stream>>>(b_edge, W_cat1, b_node, W_cat2, b_cat1, b_cat2, b4);

    // 3. fully fused gather + affine + relu + final linear -> d_out
    gather_fused<<<(NN + 15) / 16, 256, 0, stream>>>(off, cur, csr, W_edge, x,
                                                     W_cat1, W3, b4,
                                                     W_final, b_final, out, NN);
}